// Round 3
// baseline (264.911 us; speedup 1.0000x reference)
//
#include <hip/hip_runtime.h>

// RoIAlign dense (11x11 bilinear) + 3x3/s2 max pool -> [K=2048, C=256, 5, 5]
// features: [B=4, C=256, H=100, W=100] f32 (NCHW), rois: [K,5] f32
//
// R2 was L1/TA-bound: 484 tap loads per wave-roi, but samples are DENSER than
// the feature grid (spacing 0.2-1.25 px) -> only ~9 distinct rows x ~9 distinct
// columns actually needed. R3: separable bilinear with dedup.
//  - per distinct feature row: X[11] x-interp values, columns walked
//    incrementally (reuse / shift / load) -- wave-uniform scalar branches.
//  - per sample row gy: y-lerp between two register row-buffers Xa/Xb with
//    shift reuse (row indices monotone).
// All loops unrolled -> register arrays stay compile-time indexed (rule #20).
// Transpose: global dwordx4 both sides, scalar LDS (conflict-free).

constexpr int Bn = 4, Cn = 256, Hn = 100, Wn = 100;
constexpr int HWn = Hn * Wn;
constexpr float SCALE = 0.0625f;

// ---------------- Kernel 1: NCHW -> NHWC transpose (vectorized) ----------------
__global__ __launch_bounds__(256)
void nchw_to_nhwc(const float* __restrict__ in, float* __restrict__ out)
{
    __shared__ float tile[64][65];          // [channel][spatial], +1 pad
    const int s0 = blockIdx.x * 64;
    const int c0 = blockIdx.y * 64;
    const int b  = blockIdx.z;
    const int t  = threadIdx.x;

    // load: thread -> channel cl, 4 consecutive spatial
    {
        const int cl = t >> 4;              // 0..15
        const int s4 = (t & 15) * 4;        // 0..60
        const float* ip = in + ((size_t)b * Cn + c0) * HWn + s0;
#pragma unroll
        for (int pass = 0; pass < 4; ++pass) {
            const int c = pass * 16 + cl;
            if (s0 + s4 + 3 < HWn) {
                const float4 v = *(const float4*)(ip + (size_t)c * HWn + s4);
                tile[c][s4 + 0] = v.x; tile[c][s4 + 1] = v.y;
                tile[c][s4 + 2] = v.z; tile[c][s4 + 3] = v.w;
            } else {
#pragma unroll
                for (int i = 0; i < 4; ++i)
                    tile[c][s4 + i] = (s0 + s4 + i < HWn) ? ip[(size_t)c * HWn + s4 + i] : 0.0f;
            }
        }
    }
    __syncthreads();
    // store: thread -> spatial s, 4 consecutive channels
    {
        const int c4 = (t & 15) * 4;
        const int sl = t >> 4;              // 0..15
        float* op = out + ((size_t)b * HWn + s0) * Cn + c0;
#pragma unroll
        for (int pass = 0; pass < 4; ++pass) {
            const int s = pass * 16 + sl;
            if (s0 + s < HWn) {
                float4 v;
                v.x = tile[c4 + 0][s]; v.y = tile[c4 + 1][s];
                v.z = tile[c4 + 2][s]; v.w = tile[c4 + 3][s];
                *(float4*)(op + (size_t)s * Cn + c4) = v;
            }
        }
    }
}

// ---------------- Kernel 2: RoIAlign+pool with tap dedup ----------------
__global__ __launch_bounds__(256)
void roipool_nhwc(const float* __restrict__ f, const float* __restrict__ rois,
                  float* __restrict__ out)
{
    __shared__ float stage[4][800];
    const int k    = blockIdx.x;
    const int tid  = threadIdx.x;
    const int wid  = tid >> 6;
    const int lane = tid & 63;

    const float x1 = rois[k * 5 + 1] * SCALE;
    const float y1 = rois[k * 5 + 2] * SCALE;
    const float x2 = rois[k * 5 + 3] * SCALE;
    const float y2 = rois[k * 5 + 4] * SCALE;
    const int   b  = (int)rois[k * 5 + 0];

    const float* fb = f + (size_t)b * HWn * Cn + (wid * 64 + lane);

    // x-tap metadata: wave-uniform; columns forced to SGPR for scalar branches
    int   xc0[11], xc1[11];
    float wx[11];
#pragma unroll
    for (int j = 0; j < 11; ++j) {
        const float xs  = x1 + (x2 - x1) * ((float)j * 0.1f);
        const float x0f = floorf(xs);
        wx[j] = xs - x0f;
        const int x0i = (int)x0f;
        xc0[j] = __builtin_amdgcn_readfirstlane(min(max(x0i,     0), Wn - 1));
        xc1[j] = __builtin_amdgcn_readfirstlane(min(max(x0i + 1, 0), Wn - 1));
    }

    // x-interp one feature row into X[11], reusing columns (monotone walk)
    auto loadrow = [&](int r, float (&X)[11]) {
        const float* row = fb + (size_t)(r * Wn) * Cn;
        int pc0 = -9, pc1 = -9;
        float va = 0.0f, vb = 0.0f;
#pragma unroll
        for (int j = 0; j < 11; ++j) {
            const int c0 = xc0[j], c1 = xc1[j];
            if (c0 == pc0 && c1 == pc1) {
                // full reuse
            } else if (c0 == pc1) {
                va = vb;
                vb = row[(size_t)c1 * Cn];
            } else {
                va = row[(size_t)c0 * Cn];
                vb = row[(size_t)c1 * Cn];
            }
            pc0 = c0; pc1 = c1;
            X[j] = va + wx[j] * (vb - va);
        }
    };

    float Xa[11], Xb[11];
    int ra = -9, rb = -9;

    // one dense sample row gy -> 5 x-window maxes
    auto dorow = [&](int gy, float (&dst)[5]) {
        const float ys  = y1 + (y2 - y1) * ((float)gy * 0.1f);
        const float y0f = floorf(ys);
        const float wy  = ys - y0f;
        const int   y0i = (int)y0f;
        const int r0 = __builtin_amdgcn_readfirstlane(min(max(y0i,     0), Hn - 1));
        const int r1 = __builtin_amdgcn_readfirstlane(min(max(y0i + 1, 0), Hn - 1));
        if (r0 != ra) {
            if (r0 == rb) {
#pragma unroll
                for (int j = 0; j < 11; ++j) Xa[j] = Xb[j];
            } else {
                loadrow(r0, Xa);
            }
            ra = r0;
        }
        if (r1 != rb) {
            if (r1 == ra) {
#pragma unroll
                for (int j = 0; j < 11; ++j) Xb[j] = Xa[j];
            } else {
                loadrow(r1, Xb);
            }
            rb = r1;
        }
        float s[11];
#pragma unroll
        for (int j = 0; j < 11; ++j) s[j] = Xa[j] + wy * (Xb[j] - Xa[j]);
        dst[0] = fmaxf(fmaxf(s[0], s[1]), s[2]);
        dst[1] = fmaxf(fmaxf(s[2], s[3]), s[4]);
        dst[2] = fmaxf(fmaxf(s[4], s[5]), s[6]);
        dst[3] = fmaxf(fmaxf(s[6], s[7]), s[8]);
        dst[4] = fmaxf(fmaxf(s[8], s[9]), s[10]);
    };

    float o[25], xp_prev[5];
    dorow(0, xp_prev);
#pragma unroll
    for (int ph = 0; ph < 5; ++ph) {
        float t[5], nxt[5];
        dorow(2 * ph + 1, t);
#pragma unroll
        for (int pw = 0; pw < 5; ++pw) t[pw] = fmaxf(t[pw], xp_prev[pw]);
        dorow(2 * ph + 2, nxt);
#pragma unroll
        for (int pw = 0; pw < 5; ++pw) {
            o[ph * 5 + pw] = fmaxf(t[pw], nxt[pw]);
            xp_prev[pw]    = nxt[pw];
        }
    }

    // Coalesced store via per-wave LDS staging (same as R2; verified)
    const size_t obase = ((size_t)k * Cn + (size_t)wid * 64) * 25;
#pragma unroll
    for (int half = 0; half < 2; ++half) {
        if ((lane >> 5) == half) {
#pragma unroll
            for (int p = 0; p < 25; ++p)
                stage[wid][(lane & 31) * 25 + p] = o[p];
        }
        asm volatile("" ::: "memory");
#pragma unroll
        for (int i = 0; i < 13; ++i) {
            const int idx = i * 64 + lane;
            if (idx < 800)
                out[obase + (size_t)half * 800 + idx] = stage[wid][idx];
        }
        asm volatile("" ::: "memory");
    }
}

// ---------------- Fallback (R1 kernel) if workspace too small ----------------
__global__ __launch_bounds__(256)
void roialign_pool_fallback(const float* __restrict__ feats,
                            const float* __restrict__ rois,
                            float* __restrict__ out)
{
    __shared__ float smem[4][2][128];
    const int k    = blockIdx.x;
    const int tid  = threadIdx.x;
    const int wid  = tid >> 6;
    const int lane = tid & 63;

    const float x1 = rois[k * 5 + 1] * SCALE;
    const float y1 = rois[k * 5 + 2] * SCALE;
    const float x2 = rois[k * 5 + 3] * SCALE;
    const float y2 = rois[k * 5 + 4] * SCALE;
    const int   b  = (int)rois[k * 5 + 0];

    const int  p1   = 64 + lane;
    const bool act1 = (p1 < 121);
    int   o00[2], o01[2], o10[2], o11[2];
    float w00[2], w01[2], w10[2], w11[2];
#pragma unroll
    for (int r = 0; r < 2; ++r) {
        const int p  = (r == 0) ? lane : (act1 ? p1 : 120);
        const int gy = p / 11;
        const int gx = p - gy * 11;
        const float ys = y1 + (y2 - y1) * ((float)gy / 10.0f);
        const float xs = x1 + (x2 - x1) * ((float)gx / 10.0f);
        const float y0f = floorf(ys), x0f = floorf(xs);
        const float wy = ys - y0f, wxx = xs - x0f;
        const int y0i = (int)y0f, x0i = (int)x0f;
        const int y0c = min(max(y0i, 0), Hn - 1), y1c = min(max(y0i + 1, 0), Hn - 1);
        const int x0c = min(max(x0i, 0), Wn - 1), x1c = min(max(x0i + 1, 0), Wn - 1);
        o00[r] = y0c * Wn + x0c; o01[r] = y0c * Wn + x1c;
        o10[r] = y1c * Wn + x0c; o11[r] = y1c * Wn + x1c;
        w00[r] = (1.0f - wy) * (1.0f - wxx); w01[r] = (1.0f - wy) * wxx;
        w10[r] = wy * (1.0f - wxx);          w11[r] = wy * wxx;
    }
    const bool pool  = (lane < 25);
    const int  ph    = lane / 5;
    const int  pw    = lane - ph * 5;
    const int  pbase = (2 * ph) * 11 + 2 * pw;
    const float* base = feats + ((size_t)b * Cn + (size_t)wid * 64) * HWn;
    float*       op   = out + ((size_t)k * Cn + (size_t)wid * 64) * 25 + lane;
    for (int it = 0; it < 64; ++it) {
        const float* ff  = base + (size_t)it * HWn;
        float*       buf = smem[wid][it & 1];
        const float v0 = ff[o00[0]] * w00[0] + ff[o01[0]] * w01[0]
                       + ff[o10[0]] * w10[0] + ff[o11[0]] * w11[0];
        const float v1 = ff[o00[1]] * w00[1] + ff[o01[1]] * w01[1]
                       + ff[o10[1]] * w10[1] + ff[o11[1]] * w11[1];
        buf[lane] = v0;
        if (act1) buf[p1] = v1;
        if (pool) {
            float m =          buf[pbase +  0];
            m = fmaxf(m, buf[pbase +  1]);
            m = fmaxf(m, buf[pbase +  2]);
            m = fmaxf(m, buf[pbase + 11]);
            m = fmaxf(m, buf[pbase + 12]);
            m = fmaxf(m, buf[pbase + 13]);
            m = fmaxf(m, buf[pbase + 22]);
            m = fmaxf(m, buf[pbase + 23]);
            m = fmaxf(m, buf[pbase + 24]);
            op[it * 25] = m;
        }
    }
}

extern "C" void kernel_launch(void* const* d_in, const int* in_sizes, int n_in,
                              void* d_out, int out_size, void* d_ws, size_t ws_size,
                              hipStream_t stream) {
    const float* feats = (const float*)d_in[0];
    const float* rois  = (const float*)d_in[1];
    float*       out   = (float*)d_out;
    const int K = in_sizes[1] / 5;                       // 2048
    const size_t need = (size_t)Bn * Cn * HWn * sizeof(float);  // 40.96 MB

    if (ws_size >= need) {
        float* nhwc = (float*)d_ws;
        dim3 tgrid((HWn + 63) / 64, Cn / 64, Bn);        // 157 x 4 x 4
        nchw_to_nhwc<<<tgrid, 256, 0, stream>>>(feats, nhwc);
        roipool_nhwc<<<K, 256, 0, stream>>>(nhwc, rois, out);
    } else {
        roialign_pool_fallback<<<K, 256, 0, stream>>>(feats, rois, out);
    }
}

// Round 4
// 90.209 us; speedup vs baseline: 2.9366x; 2.9366x over previous
//
#include <hip/hip_runtime.h>

// RoIAlign dense (11x11 bilinear) + 3x3/s2 max pool -> [K=2048, C=256, 5, 5]
// features: [B=4, C=256, H=100, W=100] f32 (NCHW), rois: [K,5] f32
//
// R2 (45us main): lane=channel NHWC gathers, but per-lane 64-bit address math
// per tap (VALUBusy 52%) and 484 tap loads/wave-roi (2.4x col + 2.4x row
// redundancy). R3 (251us): dedup via per-tap data-dependent branches ->
// serialized loads, VGPR 148, occupancy 8% -- latency-bound disaster.
// R4: dedup the RIGHT way:
//  - all column indices/row indices readfirstlane'd to SGPRs once per roi ->
//    tap address = SGPR base + lane*4 (SALU, not VALU)
//  - x-interp each DISTINCT feature row once (Xa/Xb register cache, 2 uniform
//    branches per sample row, rows monotone) -> ~10 row-loads vs 22
//  - loadrow: 22 unconditional batched loads, then lerps (one vmcnt point)

constexpr int Bn = 4, Cn = 256, Hn = 100, Wn = 100;
constexpr int HWn = Hn * Wn;
constexpr float SCALE = 0.0625f;

// ---------------- Kernel 1: NCHW -> NHWC transpose (vectorized) ----------------
__global__ __launch_bounds__(256)
void nchw_to_nhwc(const float* __restrict__ in, float* __restrict__ out)
{
    __shared__ float tile[64][65];
    const int s0 = blockIdx.x * 64;
    const int c0 = blockIdx.y * 64;
    const int b  = blockIdx.z;
    const int t  = threadIdx.x;

    {
        const int cl = t >> 4;
        const int s4 = (t & 15) * 4;
        const float* ip = in + ((size_t)b * Cn + c0) * HWn + s0;
#pragma unroll
        for (int pass = 0; pass < 4; ++pass) {
            const int c = pass * 16 + cl;
            if (s0 + s4 + 3 < HWn) {
                const float4 v = *(const float4*)(ip + (size_t)c * HWn + s4);
                tile[c][s4 + 0] = v.x; tile[c][s4 + 1] = v.y;
                tile[c][s4 + 2] = v.z; tile[c][s4 + 3] = v.w;
            } else {
#pragma unroll
                for (int i = 0; i < 4; ++i)
                    tile[c][s4 + i] = (s0 + s4 + i < HWn) ? ip[(size_t)c * HWn + s4 + i] : 0.0f;
            }
        }
    }
    __syncthreads();
    {
        const int c4 = (t & 15) * 4;
        const int sl = t >> 4;
        float* op = out + ((size_t)b * HWn + s0) * Cn + c0;
#pragma unroll
        for (int pass = 0; pass < 4; ++pass) {
            const int s = pass * 16 + sl;
            if (s0 + s < HWn) {
                float4 v;
                v.x = tile[c4 + 0][s]; v.y = tile[c4 + 1][s];
                v.z = tile[c4 + 2][s]; v.w = tile[c4 + 3][s];
                *(float4*)(op + (size_t)s * Cn + c4) = v;
            }
        }
    }
}

// ---------------- Kernel 2: RoIAlign+pool, SGPR-addressed, row-cached ----------------
__global__ __launch_bounds__(256)
void roipool_nhwc(const float* __restrict__ f, const float* __restrict__ rois,
                  float* __restrict__ out)
{
    __shared__ float stage[4][800];
    const int k    = blockIdx.x;
    const int tid  = threadIdx.x;
    const int wid  = tid >> 6;
    const int lane = tid & 63;

    const float x1 = rois[k * 5 + 1] * SCALE;
    const float y1 = rois[k * 5 + 2] * SCALE;
    const float x2 = rois[k * 5 + 3] * SCALE;
    const float y2 = rois[k * 5 + 4] * SCALE;
    const int   b  = (int)rois[k * 5 + 0];

    // per-lane channel offset; everything else in the address is uniform
    const int ch = wid * 64 + lane;
    const float* fb = f + (size_t)b * HWn * Cn + ch;

    // ---- hoisted per-roi x metadata (columns as SGPRs, weights as regs) ----
    int   xc0[11], xc1[11];
    float wx[11];
#pragma unroll
    for (int j = 0; j < 11; ++j) {
        const float xs  = x1 + (x2 - x1) * ((float)j * 0.1f);
        const float x0f = floorf(xs);
        wx[j] = xs - x0f;                       // weight from UNCLIPPED coord
        const int x0i = (int)x0f;
        xc0[j] = __builtin_amdgcn_readfirstlane(min(max(x0i,     0), Wn - 1));
        xc1[j] = __builtin_amdgcn_readfirstlane(min(max(x0i + 1, 0), Wn - 1));
    }

    // x-interp one distinct feature row: 22 batched unconditional loads
    // (SGPR base + lane offset), single wait, then 11 lerps.
    auto loadrow = [&](int r, float (&X)[11]) {
        const size_t rowoff = (size_t)(r * Wn) * Cn;
        float ta[11], tb[11];
#pragma unroll
        for (int j = 0; j < 11; ++j) {
            ta[j] = fb[rowoff + (size_t)(xc0[j] * Cn)];
            tb[j] = fb[rowoff + (size_t)(xc1[j] * Cn)];
        }
#pragma unroll
        for (int j = 0; j < 11; ++j)
            X[j] = ta[j] + wx[j] * (tb[j] - ta[j]);
    };

    float Xa[11], Xb[11];
    int ra = -9, rb = -9;   // uniform row tags of Xa/Xb

    // one dense sample row gy -> 5 x-window maxes (row cache: <=2 uniform
    // branches; rows monotone so Xb frequently shifts into Xa)
    auto dorow = [&](int gy, float (&dst)[5]) {
        const float ys  = y1 + (y2 - y1) * ((float)gy * 0.1f);
        const float y0f = floorf(ys);
        const float wy  = ys - y0f;
        const int   y0i = (int)y0f;
        const int r0 = __builtin_amdgcn_readfirstlane(min(max(y0i,     0), Hn - 1));
        const int r1 = __builtin_amdgcn_readfirstlane(min(max(y0i + 1, 0), Hn - 1));
        if (r0 != ra) {
            if (r0 == rb) {
#pragma unroll
                for (int j = 0; j < 11; ++j) Xa[j] = Xb[j];
            } else {
                loadrow(r0, Xa);
            }
            ra = r0;
        }
        if (r1 != rb) {
            if (r1 == ra) {
#pragma unroll
                for (int j = 0; j < 11; ++j) Xb[j] = Xa[j];
            } else {
                loadrow(r1, Xb);
            }
            rb = r1;
        }
        float s[11];
#pragma unroll
        for (int j = 0; j < 11; ++j) s[j] = Xa[j] + wy * (Xb[j] - Xa[j]);
        dst[0] = fmaxf(fmaxf(s[0], s[1]), s[2]);
        dst[1] = fmaxf(fmaxf(s[2], s[3]), s[4]);
        dst[2] = fmaxf(fmaxf(s[4], s[5]), s[6]);
        dst[3] = fmaxf(fmaxf(s[6], s[7]), s[8]);
        dst[4] = fmaxf(fmaxf(s[8], s[9]), s[10]);
    };

    float o[25], xp_prev[5];
    dorow(0, xp_prev);
#pragma unroll
    for (int ph = 0; ph < 5; ++ph) {
        float t[5], nxt[5];
        dorow(2 * ph + 1, t);
#pragma unroll
        for (int pw = 0; pw < 5; ++pw) t[pw] = fmaxf(t[pw], xp_prev[pw]);
        dorow(2 * ph + 2, nxt);
#pragma unroll
        for (int pw = 0; pw < 5; ++pw) {
            o[ph * 5 + pw] = fmaxf(t[pw], nxt[pw]);
            xp_prev[pw]    = nxt[pw];
        }
    }

    // Coalesced store via per-wave LDS staging (verified R2/R3)
    const size_t obase = ((size_t)k * Cn + (size_t)wid * 64) * 25;
#pragma unroll
    for (int half = 0; half < 2; ++half) {
        if ((lane >> 5) == half) {
#pragma unroll
            for (int p = 0; p < 25; ++p)
                stage[wid][(lane & 31) * 25 + p] = o[p];
        }
        asm volatile("" ::: "memory");
#pragma unroll
        for (int i = 0; i < 13; ++i) {
            const int idx = i * 64 + lane;
            if (idx < 800)
                out[obase + (size_t)half * 800 + idx] = stage[wid][idx];
        }
        asm volatile("" ::: "memory");
    }
}

// ---------------- Fallback if workspace too small ----------------
__global__ __launch_bounds__(256)
void roialign_pool_fallback(const float* __restrict__ feats,
                            const float* __restrict__ rois,
                            float* __restrict__ out)
{
    __shared__ float smem[4][2][128];
    const int k    = blockIdx.x;
    const int tid  = threadIdx.x;
    const int wid  = tid >> 6;
    const int lane = tid & 63;

    const float x1 = rois[k * 5 + 1] * SCALE;
    const float y1 = rois[k * 5 + 2] * SCALE;
    const float x2 = rois[k * 5 + 3] * SCALE;
    const float y2 = rois[k * 5 + 4] * SCALE;
    const int   b  = (int)rois[k * 5 + 0];

    const int  p1   = 64 + lane;
    const bool act1 = (p1 < 121);
    int   o00[2], o01[2], o10[2], o11[2];
    float w00[2], w01[2], w10[2], w11[2];
#pragma unroll
    for (int r = 0; r < 2; ++r) {
        const int p  = (r == 0) ? lane : (act1 ? p1 : 120);
        const int gy = p / 11;
        const int gx = p - gy * 11;
        const float ys = y1 + (y2 - y1) * ((float)gy / 10.0f);
        const float xs = x1 + (x2 - x1) * ((float)gx / 10.0f);
        const float y0f = floorf(ys), x0f = floorf(xs);
        const float wy = ys - y0f, wxx = xs - x0f;
        const int y0i = (int)y0f, x0i = (int)x0f;
        const int y0c = min(max(y0i, 0), Hn - 1), y1c = min(max(y0i + 1, 0), Hn - 1);
        const int x0c = min(max(x0i, 0), Wn - 1), x1c = min(max(x0i + 1, 0), Wn - 1);
        o00[r] = y0c * Wn + x0c; o01[r] = y0c * Wn + x1c;
        o10[r] = y1c * Wn + x0c; o11[r] = y1c * Wn + x1c;
        w00[r] = (1.0f - wy) * (1.0f - wxx); w01[r] = (1.0f - wy) * wxx;
        w10[r] = wy * (1.0f - wxx);          w11[r] = wy * wxx;
    }
    const bool pool  = (lane < 25);
    const int  ph    = lane / 5;
    const int  pw    = lane - ph * 5;
    const int  pbase = (2 * ph) * 11 + 2 * pw;
    const float* base = feats + ((size_t)b * Cn + (size_t)wid * 64) * HWn;
    float*       op   = out + ((size_t)k * Cn + (size_t)wid * 64) * 25 + lane;
    for (int it = 0; it < 64; ++it) {
        const float* ff  = base + (size_t)it * HWn;
        float*       buf = smem[wid][it & 1];
        const float v0 = ff[o00[0]] * w00[0] + ff[o01[0]] * w01[0]
                       + ff[o10[0]] * w10[0] + ff[o11[0]] * w11[0];
        const float v1 = ff[o00[1]] * w00[1] + ff[o01[1]] * w01[1]
                       + ff[o10[1]] * w10[1] + ff[o11[1]] * w11[1];
        buf[lane] = v0;
        if (act1) buf[p1] = v1;
        if (pool) {
            float m =          buf[pbase +  0];
            m = fmaxf(m, buf[pbase +  1]);
            m = fmaxf(m, buf[pbase +  2]);
            m = fmaxf(m, buf[pbase + 11]);
            m = fmaxf(m, buf[pbase + 12]);
            m = fmaxf(m, buf[pbase + 13]);
            m = fmaxf(m, buf[pbase + 22]);
            m = fmaxf(m, buf[pbase + 23]);
            m = fmaxf(m, buf[pbase + 24]);
            op[it * 25] = m;
        }
    }
}

extern "C" void kernel_launch(void* const* d_in, const int* in_sizes, int n_in,
                              void* d_out, int out_size, void* d_ws, size_t ws_size,
                              hipStream_t stream) {
    const float* feats = (const float*)d_in[0];
    const float* rois  = (const float*)d_in[1];
    float*       out   = (float*)d_out;
    const int K = in_sizes[1] / 5;                       // 2048
    const size_t need = (size_t)Bn * Cn * HWn * sizeof(float);  // 40.96 MB

    if (ws_size >= need) {
        float* nhwc = (float*)d_ws;
        dim3 tgrid((HWn + 63) / 64, Cn / 64, Bn);        // 157 x 4 x 4
        nchw_to_nhwc<<<tgrid, 256, 0, stream>>>(feats, nhwc);
        roipool_nhwc<<<K, 256, 0, stream>>>(nhwc, rois, out);
    } else {
        roialign_pool_fallback<<<K, 256, 0, stream>>>(feats, rois, out);
    }
}

// Round 5
// 57.958 us; speedup vs baseline: 4.5708x; 1.5565x over previous
//
#include <hip/hip_runtime.h>

// RoIAlign dense (11x11 bilinear) + 3x3/s2 max pool -> [K=2048, C=256, 5, 5]
// features: [B=4, C=256, H=100, W=100] f32 (NCHW), rois: [K,5] f32
//
// History: R2 (45us main) static NHWC lane=channel, VALUBusy 52% (per-lane
// 64-bit address math per tap). R3/R4 tried load dedup via branches ->
// VGPR 148, occupancy 9%, loads serialized behind branches: 251/75us.
// Lesson: static pipelining > dedup. R5 = R2 structure, zero branches, plus:
//  - all row/col indices readfirstlane'd -> tap pointers are SGPR; per-tap
//    per-lane work is just global_load v,[v_ch],s[ptr] + the lerp FMAs.
//  - pooled rows written to LDS stage immediately (no o[25] live) -> lower
//    VGPR, higher occupancy.

constexpr int Bn = 4, Cn = 256, Hn = 100, Wn = 100;
constexpr int HWn = Hn * Wn;
constexpr float SCALE = 0.0625f;

// ---------------- Kernel 1: NCHW -> NHWC transpose (vectorized) ----------------
__global__ __launch_bounds__(256)
void nchw_to_nhwc(const float* __restrict__ in, float* __restrict__ out)
{
    __shared__ float tile[64][65];
    const int s0 = blockIdx.x * 64;
    const int c0 = blockIdx.y * 64;
    const int b  = blockIdx.z;
    const int t  = threadIdx.x;

    {
        const int cl = t >> 4;
        const int s4 = (t & 15) * 4;
        const float* ip = in + ((size_t)b * Cn + c0) * HWn + s0;
#pragma unroll
        for (int pass = 0; pass < 4; ++pass) {
            const int c = pass * 16 + cl;
            if (s0 + s4 + 3 < HWn) {
                const float4 v = *(const float4*)(ip + (size_t)c * HWn + s4);
                tile[c][s4 + 0] = v.x; tile[c][s4 + 1] = v.y;
                tile[c][s4 + 2] = v.z; tile[c][s4 + 3] = v.w;
            } else {
#pragma unroll
                for (int i = 0; i < 4; ++i)
                    tile[c][s4 + i] = (s0 + s4 + i < HWn) ? ip[(size_t)c * HWn + s4 + i] : 0.0f;
            }
        }
    }
    __syncthreads();
    {
        const int c4 = (t & 15) * 4;
        const int sl = t >> 4;
        float* op = out + ((size_t)b * HWn + s0) * Cn + c0;
#pragma unroll
        for (int pass = 0; pass < 4; ++pass) {
            const int s = pass * 16 + sl;
            if (s0 + s < HWn) {
                float4 v;
                v.x = tile[c4 + 0][s]; v.y = tile[c4 + 1][s];
                v.z = tile[c4 + 2][s]; v.w = tile[c4 + 3][s];
                *(float4*)(op + (size_t)s * Cn + c4) = v;
            }
        }
    }
}

// ---------------- Kernel 2: RoIAlign+pool, static, SGPR-addressed ----------------
__global__ __launch_bounds__(256)
void roipool_nhwc(const float* __restrict__ f, const float* __restrict__ rois,
                  float* __restrict__ out)
{
    __shared__ float stage[4][64 * 25];          // 25.6 KB: [wave][ch_local*25+idx]
    const int k    = blockIdx.x;
    const int tid  = threadIdx.x;
    const int wid  = tid >> 6;
    const int lane = tid & 63;

    const float x1 = rois[k * 5 + 1] * SCALE;
    const float y1 = rois[k * 5 + 2] * SCALE;
    const float x2 = rois[k * 5 + 3] * SCALE;
    const float y2 = rois[k * 5 + 4] * SCALE;
    const int   b  = __builtin_amdgcn_readfirstlane((int)rois[k * 5 + 0]);

    const int ch = wid * 64 + lane;              // per-lane channel (only VGPR in addr)
    const float* fb = f + (size_t)b * HWn * Cn;  // uniform base

    // per-roi x-tap metadata: element offsets as SGPRs, weights per-lane
    int   xo0[11], xo1[11];
    float wx[11];
#pragma unroll
    for (int j = 0; j < 11; ++j) {
        const float xs  = x1 + (x2 - x1) * ((float)j * 0.1f);
        const float x0f = floorf(xs);
        wx[j] = xs - x0f;                        // weight from UNCLIPPED coord
        const int x0i = (int)x0f;
        xo0[j] = __builtin_amdgcn_readfirstlane(min(max(x0i,     0), Wn - 1)) * Cn;
        xo1[j] = __builtin_amdgcn_readfirstlane(min(max(x0i + 1, 0), Wn - 1)) * Cn;
    }

    // one dense sample row gy -> 5 x-window maxes; fully static, no branches
    auto dorow = [&](int gy, float (&dst)[5]) {
        const float ys  = y1 + (y2 - y1) * ((float)gy * 0.1f);
        const float y0f = floorf(ys);
        const float wy  = ys - y0f;
        const int   y0i = (int)y0f;
        const int r0 = __builtin_amdgcn_readfirstlane(min(max(y0i,     0), Hn - 1));
        const int r1 = __builtin_amdgcn_readfirstlane(min(max(y0i + 1, 0), Hn - 1));
        const float* rp0 = fb + (size_t)(r0 * Wn) * Cn;  // uniform row pointers
        const float* rp1 = fb + (size_t)(r1 * Wn) * Cn;
        float s[11];
#pragma unroll
        for (int j = 0; j < 11; ++j) {
            const float* p00 = rp0 + xo0[j];     // uniform tap pointers (SALU)
            const float* p01 = rp0 + xo1[j];
            const float* p10 = rp1 + xo0[j];
            const float* p11 = rp1 + xo1[j];
            const float t00 = p00[ch];
            const float t01 = p01[ch];
            const float t10 = p10[ch];
            const float t11 = p11[ch];
            const float X0 = t00 + wx[j] * (t01 - t00);
            const float X1 = t10 + wx[j] * (t11 - t10);
            s[j] = X0 + wy * (X1 - X0);
        }
        dst[0] = fmaxf(fmaxf(s[0], s[1]), s[2]);
        dst[1] = fmaxf(fmaxf(s[2], s[3]), s[4]);
        dst[2] = fmaxf(fmaxf(s[4], s[5]), s[6]);
        dst[3] = fmaxf(fmaxf(s[6], s[7]), s[8]);
        dst[4] = fmaxf(fmaxf(s[8], s[9]), s[10]);
    };

    float xp_prev[5];
    dorow(0, xp_prev);
    float* st = &stage[wid][lane * 25];
#pragma unroll
    for (int ph = 0; ph < 5; ++ph) {
        float t[5], nxt[5];
        dorow(2 * ph + 1, t);
        dorow(2 * ph + 2, nxt);
#pragma unroll
        for (int pw = 0; pw < 5; ++pw) {
            st[ph * 5 + pw] = fmaxf(fmaxf(xp_prev[pw], t[pw]), nxt[pw]);
            xp_prev[pw]     = nxt[pw];
        }
    }

    // same-wave LDS in-order; stop compiler reordering global stores before writes
    asm volatile("" ::: "memory");

    const size_t obase = ((size_t)k * Cn + (size_t)wid * 64) * 25;
#pragma unroll
    for (int i = 0; i < 25; ++i)
        out[obase + i * 64 + lane] = stage[wid][i * 64 + lane];
}

// ---------------- Fallback if workspace too small ----------------
__global__ __launch_bounds__(256)
void roialign_pool_fallback(const float* __restrict__ feats,
                            const float* __restrict__ rois,
                            float* __restrict__ out)
{
    __shared__ float smem[4][2][128];
    const int k    = blockIdx.x;
    const int tid  = threadIdx.x;
    const int wid  = tid >> 6;
    const int lane = tid & 63;

    const float x1 = rois[k * 5 + 1] * SCALE;
    const float y1 = rois[k * 5 + 2] * SCALE;
    const float x2 = rois[k * 5 + 3] * SCALE;
    const float y2 = rois[k * 5 + 4] * SCALE;
    const int   b  = (int)rois[k * 5 + 0];

    const int  p1   = 64 + lane;
    const bool act1 = (p1 < 121);
    int   o00[2], o01[2], o10[2], o11[2];
    float w00[2], w01[2], w10[2], w11[2];
#pragma unroll
    for (int r = 0; r < 2; ++r) {
        const int p  = (r == 0) ? lane : (act1 ? p1 : 120);
        const int gy = p / 11;
        const int gx = p - gy * 11;
        const float ys = y1 + (y2 - y1) * ((float)gy / 10.0f);
        const float xs = x1 + (x2 - x1) * ((float)gx / 10.0f);
        const float y0f = floorf(ys), x0f = floorf(xs);
        const float wy = ys - y0f, wxx = xs - x0f;
        const int y0i = (int)y0f, x0i = (int)x0f;
        const int y0c = min(max(y0i, 0), Hn - 1), y1c = min(max(y0i + 1, 0), Hn - 1);
        const int x0c = min(max(x0i, 0), Wn - 1), x1c = min(max(x0i + 1, 0), Wn - 1);
        o00[r] = y0c * Wn + x0c; o01[r] = y0c * Wn + x1c;
        o10[r] = y1c * Wn + x0c; o11[r] = y1c * Wn + x1c;
        w00[r] = (1.0f - wy) * (1.0f - wxx); w01[r] = (1.0f - wy) * wxx;
        w10[r] = wy * (1.0f - wxx);          w11[r] = wy * wxx;
    }
    const bool pool  = (lane < 25);
    const int  ph    = lane / 5;
    const int  pw    = lane - ph * 5;
    const int  pbase = (2 * ph) * 11 + 2 * pw;
    const float* base = feats + ((size_t)b * Cn + (size_t)wid * 64) * HWn;
    float*       op   = out + ((size_t)k * Cn + (size_t)wid * 64) * 25 + lane;
    for (int it = 0; it < 64; ++it) {
        const float* ff  = base + (size_t)it * HWn;
        float*       buf = smem[wid][it & 1];
        const float v0 = ff[o00[0]] * w00[0] + ff[o01[0]] * w01[0]
                       + ff[o10[0]] * w10[0] + ff[o11[0]] * w11[0];
        const float v1 = ff[o00[1]] * w00[1] + ff[o01[1]] * w01[1]
                       + ff[o10[1]] * w10[1] + ff[o11[1]] * w11[1];
        buf[lane] = v0;
        if (act1) buf[p1] = v1;
        if (pool) {
            float m =          buf[pbase +  0];
            m = fmaxf(m, buf[pbase +  1]);
            m = fmaxf(m, buf[pbase +  2]);
            m = fmaxf(m, buf[pbase + 11]);
            m = fmaxf(m, buf[pbase + 12]);
            m = fmaxf(m, buf[pbase + 13]);
            m = fmaxf(m, buf[pbase + 22]);
            m = fmaxf(m, buf[pbase + 23]);
            m = fmaxf(m, buf[pbase + 24]);
            op[it * 25] = m;
        }
    }
}

extern "C" void kernel_launch(void* const* d_in, const int* in_sizes, int n_in,
                              void* d_out, int out_size, void* d_ws, size_t ws_size,
                              hipStream_t stream) {
    const float* feats = (const float*)d_in[0];
    const float* rois  = (const float*)d_in[1];
    float*       out   = (float*)d_out;
    const int K = in_sizes[1] / 5;                       // 2048
    const size_t need = (size_t)Bn * Cn * HWn * sizeof(float);  // 40.96 MB

    if (ws_size >= need) {
        float* nhwc = (float*)d_ws;
        dim3 tgrid((HWn + 63) / 64, Cn / 64, Bn);        // 157 x 4 x 4
        nchw_to_nhwc<<<tgrid, 256, 0, stream>>>(feats, nhwc);
        roipool_nhwc<<<K, 256, 0, stream>>>(nhwc, rois, out);
    } else {
        roialign_pool_fallback<<<K, 256, 0, stream>>>(feats, rois, out);
    }
}